// Round 20
// baseline (362.906 us; speedup 1.0000x reference)
//
#include <hip/hip_runtime.h>
#include <math.h>

// ---------------------------------------------------------------------------
// Attention: B=4, S=2048, E=1024, H=8, O=128 (fp32 in/out)
// Split-bf16 (hi+lo) MFMA for x->QK and QK^T (precision-critical: score sd
// ~1500 exp2-domain log-units -> split terms are load-bearing; do NOT cut),
// plain bf16 for V / PV / ctx@Wo. Flash-attention (no S x S materialize).
// R1-R5: see history. R6: 2-barrier attn (369.8us total).
// R7/R8: barrier-free attn REGRESSED. R9: +setprio, attn 168.7us. BEST base.
// R10: dbuf NEUTRAL (latency ruled out; volume untested). R11: occupancy
//     REGRESSED. R12: defer-max NEUTRAL. R13/R14: anti-phase NEUTRAL;
//     gemm0 V-block lo-skip KEPT. R15-R17: coalesced preps KEPT (346.0).
// R18-R23: XCD-clustered gemm remap + fused preps KEPT (-10us, 336.1).
// R24/R25: P_s stride 68: conflicts 9.4M->8.4M but dur FLAT (338.9, noise)
//     -> bank conflicts NOT on attn critical path. PS=68 kept (harmless).
// R26 (this round): attn Kl DIRECT-FROM-L2 with 1-ahead register pipeline;
//     Kl_s removed (LDS 66.6->50.7KB). Tests the untested facet: staged
//     DRAIN VOLUME (48->32KB/iter at the barrier; R10 only tested latency).
//     Kl is L2-resident 16KB/tile; loads issued one ni-block ahead, hidden
//     under hh/lh MFMAs. Unlike R7: 2/3 operands still LDS-staged.
// ---------------------------------------------------------------------------

typedef __attribute__((ext_vector_type(8))) short bf16x8;   // 8 bf16 (4 VGPRs)
typedef __attribute__((ext_vector_type(4))) float f32x4;
typedef __attribute__((ext_vector_type(4))) short s16x4;

#define MFMA(a, b, c) __builtin_amdgcn_mfma_f32_16x16x32_bf16((a), (b), (c), 0, 0, 0)
#define GLB(p) ((const __attribute__((address_space(1))) void*)(p))
#define LDS(p) ((__attribute__((address_space(3))) void*)(p))

#if __has_builtin(__builtin_amdgcn_exp2f)
#define EXP2F(x) __builtin_amdgcn_exp2f(x)
#else
#define EXP2F(x) exp2f(x)
#endif

__device__ __forceinline__ short f2bf(float f) {
    union { float f; unsigned u; } v; v.f = f;
    unsigned r = v.u + 0x7fffu + ((v.u >> 16) & 1u);   // RNE
    return (short)(r >> 16);
}
__device__ __forceinline__ float bf2f(short s) {
    union { unsigned u; float f; } v; v.u = ((unsigned)(unsigned short)s) << 16;
    return v.f;
}

// ---------------- fused prep kernel ----------------
// blocks [0,2048): x -> xh/xl split (float4/short4 vectorized)
// blocks [2048,3328): Wq/Wk/Wv -> Wt transpose (LDS tile, coalesced)
// blocks [3328,4352): Wo -> Wo^T bf16 transpose (LDS tile, coalesced)
__global__ __launch_bounds__(256) void prep_all(
    const float* __restrict__ x, short* __restrict__ xh, short* __restrict__ xl,
    const float* __restrict__ Wq, const float* __restrict__ Wk,
    const float* __restrict__ Wv, short* __restrict__ wth, short* __restrict__ wtl,
    const float* __restrict__ Wo, short* __restrict__ wot) {
    __shared__ float tile[32][33];
    const int bid = blockIdx.x, t = threadIdx.x;

    if (bid < 2048) {
        for (int i = bid * 256 + t; i < 2097152; i += 2048 * 256) {
            f32x4 v = *(const f32x4*)&x[(size_t)i * 4];
            s16x4 h, l;
            for (int j = 0; j < 4; ++j) {
                float f = v[j];
                short hh = f2bf(f);
                h[j] = hh;
                l[j] = f2bf(f - bf2f(hh));
            }
            *(s16x4*)&xh[(size_t)i * 4] = h;
            *(s16x4*)&xl[(size_t)i * 4] = l;
        }
        return;
    }

    if (bid < 3328) {
        const int l = bid - 2048;                   // old grid (32,4,10)
        const int m = l / 128, rem = l % 128;
        const int o0 = (rem / 32) * 32, k0 = (rem % 32) * 32;
        const float* src = (m < 8) ? (Wq + (size_t)m * 1024 * 128) : (m == 8 ? Wk : Wv);
        const int base_n = (m < 8) ? m * 128 : (m == 8 ? 1024 : 1152);
        {
            int tx = t & 31, ty = t >> 5;           // coalesced [k][o] loads
            for (int p = 0; p < 4; ++p)
                tile[ty + p * 8][tx] = src[(size_t)(k0 + ty + p * 8) * 128 + o0 + tx];
        }
        __syncthreads();
        {
            int kx = (t & 15) * 2, oy = t >> 4;     // coalesced [n][k] stores
            for (int p = 0; p < 2; ++p) {
                int o = oy + p * 16;
                float f0 = tile[kx][o], f1 = tile[kx + 1][o];
                short h0 = f2bf(f0), h1 = f2bf(f1);
                short l0 = f2bf(f0 - bf2f(h0)), l1 = f2bf(f1 - bf2f(h1));
                size_t oidx = (size_t)(base_n + o0 + o) * 1024 + k0 + kx;
                *(unsigned*)&wth[oidx] = (unsigned)(unsigned short)h0 |
                                         ((unsigned)(unsigned short)h1 << 16);
                *(unsigned*)&wtl[oidx] = (unsigned)(unsigned short)l0 |
                                         ((unsigned)(unsigned short)l1 << 16);
            }
        }
        return;
    }

    {
        const int l = bid - 3328;                   // old grid (32,32)
        const int k0 = (l & 31) * 32, e0 = (l >> 5) * 32;
        {
            int tx = t & 31, ty = t >> 5;
            for (int p = 0; p < 4; ++p)
                tile[ty + p * 8][tx] = Wo[(size_t)(k0 + ty + p * 8) * 1024 + e0 + tx];
        }
        __syncthreads();
        {
            int kx = (t & 15) * 2, ey = t >> 4;
            for (int p = 0; p < 2; ++p) {
                int e = ey + p * 16;
                float f0 = tile[kx][e], f1 = tile[kx + 1][e];
                short h0 = f2bf(f0), h1 = f2bf(f1);
                size_t oidx = (size_t)(e0 + e) * 1024 + k0 + kx;
                *(unsigned*)&wot[oidx] = (unsigned)(unsigned short)h0 |
                                         ((unsigned)(unsigned short)h1 << 16);
            }
        }
    }
}

// ---------------- GEMM: C(M x N) = A(M x 1024) @ Bt(N x 1024)^T ----------------
// K-tiles and epilogue staging share one LDS allocation (disjoint lifetimes,
// barrier-separated): 33.8 KB -> 4 blocks/CU.
// y==9 (V block) only consumes the hi result -> skip lo staging + lo MFMAs.
// XCD-clustered remap (verified -10us w/ prep fusion): XCD c owns
// bx===c(mod 8) x all by -> per-XCD set ~13 MB, A-reuse L2-resident.
template <int MODE>
__global__ __launch_bounds__(256, 4) void gemm_k(
    const short* __restrict__ Ah, const short* __restrict__ Al,
    const short* __restrict__ Bth, const short* __restrict__ Btl,
    short* __restrict__ qh, short* __restrict__ ql,
    short* __restrict__ kh, short* __restrict__ kl,
    short* __restrict__ vt, float* __restrict__ outf) {
    constexpr int K = 1024;
    constexpr int NY = (MODE == 0) ? 10 : 8;
    __shared__ __align__(16) char smem[33792];
    short* As_h = (short*)smem;                 // 128x32 = 8192 B
    short* Bs_h = (short*)(smem + 8192);
    short* As_l = (short*)(smem + 16384);       // MODE 0 only
    short* Bs_l = (short*)(smem + 24576);
    unsigned* Ep = (unsigned*)smem;             // 64x132 u32 = 33792 B (epilogue)

    const int t = threadIdx.x;
    const int L = blockIdx.y * gridDim.x + blockIdx.x;
    const int rg = L / (8 * NY), rr = L % (8 * NY);
    const int bx = rg * 8 + (rr & 7), by = rr >> 3;
    const int m0 = bx * 128, n0 = by * 128;
    const int wave = t >> 6, lane = t & 63;
    const int wr = wave >> 1, wc = wave & 1;
    const int quad = lane >> 4, l16 = lane & 15;
    const bool needLo = (MODE == 0) && (by < 9);   // V block skips lo

    f32x4 acc[4][4];
    for (int i = 0; i < 4; ++i)
        for (int j = 0; j < 4; ++j) acc[i][j] = (f32x4){0.f, 0.f, 0.f, 0.f};

    for (int kb = 0; kb < K / 32; ++kb) {
        __syncthreads();
        // DMA staging: each matrix = 512 slots of 16 B; 2 wave-insts per wave.
        for (int i = 0; i < 2; ++i) {
            int slot = (wave * 2 + i) * 64 + lane;
            int row = slot >> 2, ch = slot & 3;
            int ldsoff = (wave * 2 + i) * 512;  // shorts; +lane*16B by HW
            size_t ga = (size_t)(m0 + row) * K + kb * 32 + ch * 8;
            size_t gb = (size_t)(n0 + row) * K + kb * 32 + ch * 8;
            __builtin_amdgcn_global_load_lds(GLB(Ah + ga), LDS(&As_h[ldsoff]), 16, 0, 0);
            __builtin_amdgcn_global_load_lds(GLB(Bth + gb), LDS(&Bs_h[ldsoff]), 16, 0, 0);
            if constexpr (MODE == 0) {
                if (needLo) {
                    __builtin_amdgcn_global_load_lds(GLB(Al + ga), LDS(&As_l[ldsoff]), 16, 0, 0);
                    __builtin_amdgcn_global_load_lds(GLB(Btl + gb), LDS(&Bs_l[ldsoff]), 16, 0, 0);
                }
            }
        }
        __syncthreads();

        bf16x8 a[4], b[4];
        for (int mi = 0; mi < 4; ++mi)
            a[mi] = *(const bf16x8*)&As_h[(wr * 64 + mi * 16 + l16) * 32 + quad * 8];
        for (int ni = 0; ni < 4; ++ni)
            b[ni] = *(const bf16x8*)&Bs_h[(wc * 64 + ni * 16 + l16) * 32 + quad * 8];
        for (int mi = 0; mi < 4; ++mi)
            for (int ni = 0; ni < 4; ++ni)
                acc[mi][ni] = MFMA(a[mi], b[ni], acc[mi][ni]);
        if constexpr (MODE == 0) {
            if (needLo) {
                bf16x8 al[4], bl[4];
                for (int mi = 0; mi < 4; ++mi)
                    al[mi] = *(const bf16x8*)&As_l[(wr * 64 + mi * 16 + l16) * 32 + quad * 8];
                for (int ni = 0; ni < 4; ++ni)
                    bl[ni] = *(const bf16x8*)&Bs_l[(wc * 64 + ni * 16 + l16) * 32 + quad * 8];
                for (int mi = 0; mi < 4; ++mi)
                    for (int ni = 0; ni < 4; ++ni) {
                        acc[mi][ni] = MFMA(a[mi], bl[ni], acc[mi][ni]);
                        acc[mi][ni] = MFMA(al[mi], b[ni], acc[mi][ni]);
                    }
            }
        }
    }

    // LDS-staged epilogue (C/D layout: col=l16, row=quad*4+r).
    // Q columns pre-scaled by (1/sqrt(128))*log2(e) for exp2-domain softmax.
    const float qscale = 0.12753102455195157f;
    for (int p = 0; p < 2; ++p) {
        __syncthreads();   // also separates K-loop tile reads from Ep writes
        if (wr == p) {
            for (int mi = 0; mi < 4; ++mi) {
                int rl = mi * 16 + quad * 4;
                for (int ni = 0; ni < 4; ++ni) {
                    int cl = wc * 64 + ni * 16 + l16;
                    for (int r = 0; r < 4; ++r) {
                        float v = acc[mi][ni][r];
                        unsigned pk;
                        if constexpr (MODE == 0) {
                            if (by < 8) v *= qscale;
                            short hv = f2bf(v);
                            short lv = f2bf(v - bf2f(hv));
                            pk = (unsigned)(unsigned short)hv |
                                 ((unsigned)(unsigned short)lv << 16);
                        } else {
                            union { float f; unsigned u; } cv; cv.f = v; pk = cv.u;
                        }
                        Ep[(rl + r) * 132 + cl] = pk;
                    }
                }
            }
        }
        __syncthreads();

        if constexpr (MODE == 1) {
            for (int j = 0; j < 8; ++j) {
                int cid = t + j * 256;
                int row = cid >> 5, c = cid & 31;
                f32x4 val;
                for (int q = 0; q < 4; ++q) {
                    union { unsigned u; float f; } cv;
                    cv.u = Ep[row * 132 + c * 4 + q];
                    val[q] = cv.f;
                }
                int gr = m0 + p * 64 + row;
                *(f32x4*)&outf[(size_t)gr * 1024 + n0 + c * 4] = val;
            }
        } else if (by < 9) {
            for (int j = 0; j < 4; ++j) {
                int cid = t + j * 256;
                int row = cid >> 4, c = cid & 15;
                bf16x8 hv, lv;
                for (int q = 0; q < 8; ++q) {
                    unsigned w = Ep[row * 132 + c * 8 + q];
                    hv[q] = (short)(w & 0xffffu);
                    lv[q] = (short)(w >> 16);
                }
                int gr = m0 + p * 64 + row;
                int bb = gr >> 11, s = gr & 2047;
                if (by < 8) {
                    size_t base = (((size_t)(bb * 8 + (n0 >> 7))) * 2048 + s) * 128 + c * 8;
                    *(bf16x8*)&qh[base] = hv;
                    *(bf16x8*)&ql[base] = lv;
                } else {
                    size_t base = ((size_t)bb * 2048 + s) * 128 + c * 8;
                    *(bf16x8*)&kh[base] = hv;
                    *(bf16x8*)&kl[base] = lv;
                }
            }
        } else {
            for (int j = 0; j < 4; ++j) {
                int cid = t + j * 256;
                int d = cid >> 3, sc = cid & 7;
                bf16x8 hv;
                for (int q = 0; q < 8; ++q) {
                    unsigned w = Ep[(sc * 8 + q) * 132 + d];
                    hv[q] = (short)(w & 0xffffu);
                }
                int gr0 = m0 + p * 64 + sc * 8;
                int bb = gr0 >> 11, s0 = gr0 & 2047;
                *(bf16x8*)&vt[((size_t)bb * 128 + d) * 2048 + s0] = hv;
            }
        }
    }
}

// ---------------- flash attention (R26: Kl direct from L2) ----------------
// grid (S/128, B*H); 4 waves x 32 query rows (2 m-blocks); BN=64 keys/iter.
// Kh/V staged via global_load_lds (XOR-swizzled) between the two barriers;
// Kl read DIRECT from global (L2-resident 16KB/tile) with a 1-ahead
// register pipeline (4 fragments per ni-block, issued under hh/lh MFMAs).
// setprio(1) around MFMA clusters. P_s stride 68 (R24, kept).
__global__ __launch_bounds__(256, 2) void attn_k(
    const short* __restrict__ qh, const short* __restrict__ ql,
    const short* __restrict__ kh, const short* __restrict__ kl,
    const short* __restrict__ vt, short* __restrict__ ctx) {
    constexpr int S = 2048, D = 128;
    constexpr int PS = 68;              // P_s row stride (shorts)
    __shared__ short Kh_s[64 * 128];    // swizzled, no pad (16 KB)
    __shared__ short Vt_s[128 * 64];    // swizzled, no pad (16 KB)
    __shared__ short P_s[128 * PS];     // per-wave 32-row slices (17.4 KB)

    const int bh = blockIdx.y, b = bh >> 3, h = bh & 7;
    const int q0 = blockIdx.x * 128;
    const int t = threadIdx.x, wave = t >> 6, lane = t & 63;
    const int quad = lane >> 4, l16 = lane & 15;
    const int e8 = l16 & 7;             // xor-swizzle key

    // ones B-fragment: B[n=l16][k] = (n==0) ? 1.0bf16 : 0  -> C[., col0] = rowsum
    bf16x8 bones;
    {
        short o = (l16 == 0) ? (short)0x3F80 : (short)0;
        for (int j = 0; j < 8; ++j) bones[j] = o;
    }

    // Q fragments (A-layout A[m=l16][k=quad*8+j]), 2 m-blocks x 4 k-chunks
    bf16x8 qfh[2][4], qfl[2][4];
    for (int mb = 0; mb < 2; ++mb) {
        size_t qbase = ((size_t)(b * 8 + h) * S + q0 + wave * 32 + mb * 16 + l16) * D + quad * 8;
        for (int c = 0; c < 4; ++c) {
            qfh[mb][c] = *(const bf16x8*)(qh + qbase + c * 32);
            qfl[mb][c] = *(const bf16x8*)(ql + qbase + c * 32);
        }
    }

    float mrow[2][4];
    f32x4 oacc[2][8], lacc[2];
    for (int mb = 0; mb < 2; ++mb) {
        for (int r = 0; r < 4; ++r) mrow[mb][r] = -INFINITY;
        for (int oi = 0; oi < 8; ++oi) oacc[mb][oi] = (f32x4){0.f, 0.f, 0.f, 0.f};
        lacc[mb] = (f32x4){0.f, 0.f, 0.f, 0.f};
    }

    const short* klB = kl + (size_t)b * S * D;

    for (int kt = 0; kt < S / 64; ++kt) {
        __syncthreads();  // protect LDS reuse
        // --- stage K hi: 64 rows x 128 (Kl is read direct; not staged) ---
        {
            int pch = lane & 15;
            for (int i = 0; i < 4; ++i) {
                int rk = wave * 16 + i * 4 + (lane >> 4);
                int j = pch ^ (rk & 7);
                size_t g = ((size_t)b * S + kt * 64 + rk) * D + j * 8;
                int ldsoff = (wave * 16 + i * 4) * 128;
                __builtin_amdgcn_global_load_lds(GLB(kh + g), LDS(&Kh_s[ldsoff]), 16, 0, 0);
            }
        }
        // --- stage V^T: 128 rows(o) x 64(s) ---
        {
            int pch = lane & 7;
            for (int i = 0; i < 4; ++i) {
                int rv = wave * 32 + i * 8 + (lane >> 3);
                int j = pch ^ (rv & 7);
                size_t g = ((size_t)b * D + rv) * S + kt * 64 + j * 8;
                int ldsoff = (wave * 32 + i * 8) * 64;
                __builtin_amdgcn_global_load_lds(GLB(vt + g), LDS(&Vt_s[ldsoff]), 16, 0, 0);
            }
        }
        __syncthreads();

        // --- S' = Q' K^T (split: hh + lh + hl); scores already * scale*log2e ---
        // Kl fragments direct from global, 1 ni-block ahead (L2-resident).
        const short* klT = klB + (size_t)(kt * 64) * D;
        f32x4 sacc[2][4];
        for (int mb = 0; mb < 2; ++mb)
            for (int ni = 0; ni < 4; ++ni) sacc[mb][ni] = (f32x4){0.f, 0.f, 0.f, 0.f};
        bf16x8 kfl[4];
        {
            const short* r0 = klT + (size_t)l16 * D + quad * 8;
            for (int c = 0; c < 4; ++c) kfl[c] = *(const bf16x8*)(r0 + c * 32);
        }
        for (int ni = 0; ni < 4; ++ni) {
            bf16x8 nfl[4];
            if (ni < 3) {
                const short* rn = klT + (size_t)((ni + 1) * 16 + l16) * D + quad * 8;
                for (int c = 0; c < 4; ++c) nfl[c] = *(const bf16x8*)(rn + c * 32);
            }
            for (int c = 0; c < 4; ++c) {
                int off = (ni * 16 + l16) * 128 + ((c * 4 + quad) ^ e8) * 8;
                bf16x8 kbh = *(const bf16x8*)&Kh_s[off];
                __builtin_amdgcn_s_setprio(1);
                for (int mb = 0; mb < 2; ++mb) {
                    sacc[mb][ni] = MFMA(qfh[mb][c], kbh, sacc[mb][ni]);
                    sacc[mb][ni] = MFMA(qfl[mb][c], kbh, sacc[mb][ni]);
                    sacc[mb][ni] = MFMA(qfh[mb][c], kfl[c], sacc[mb][ni]);
                }
                __builtin_amdgcn_s_setprio(0);
            }
            if (ni < 3)
                for (int c = 0; c < 4; ++c) kfl[c] = nfl[c];
        }

        // --- online softmax (exp2 domain); rows quad*4+r per m-block ---
        for (int mb = 0; mb < 2; ++mb) {
            for (int r = 0; r < 4; ++r) {
                float mx = fmaxf(fmaxf(sacc[mb][0][r], sacc[mb][1][r]),
                                 fmaxf(sacc[mb][2][r], sacc[mb][3][r]));
                for (int off = 8; off; off >>= 1) mx = fmaxf(mx, __shfl_xor(mx, off));
                float mnew = fmaxf(mrow[mb][r], mx);
                float alpha = EXP2F(mrow[mb][r] - mnew);
                mrow[mb][r] = mnew;
                for (int ni = 0; ni < 4; ++ni)
                    sacc[mb][ni][r] = EXP2F(sacc[mb][ni][r] - mnew);
                lacc[mb][r] *= alpha;
                for (int oi = 0; oi < 8; ++oi) oacc[mb][oi][r] *= alpha;
            }
            // P -> LDS (C-layout -> A-layout); round-half-up bf16 (2 ops)
            for (int ni = 0; ni < 4; ++ni)
                for (int r = 0; r < 4; ++r) {
                    union { float f; unsigned u; } cv; cv.f = sacc[mb][ni][r];
                    P_s[(wave * 32 + mb * 16 + quad * 4 + r) * PS + ni * 16 + l16] =
                        (short)((cv.u + 0x8000u) >> 16);
                }
        }

        // --- O += P @ V ; l += P @ ones (MFMA) ---
        for (int c2 = 0; c2 < 2; ++c2) {
            bf16x8 pa[2];
            for (int mb = 0; mb < 2; ++mb) {
                pa[mb] = *(const bf16x8*)&P_s[(wave * 32 + mb * 16 + l16) * PS + c2 * 32 + quad * 8];
                lacc[mb] = MFMA(pa[mb], bones, lacc[mb]);
            }
            for (int oi = 0; oi < 8; ++oi) {
                int off = (oi * 16 + l16) * 64 + ((c2 * 4 + quad) ^ e8) * 8;
                bf16x8 vb = *(const bf16x8*)&Vt_s[off];
                __builtin_amdgcn_s_setprio(1);
                for (int mb = 0; mb < 2; ++mb)
                    oacc[mb][oi] = MFMA(pa[mb], vb, oacc[mb][oi]);
                __builtin_amdgcn_s_setprio(0);
            }
        }
    }

    // epilogue: ctx[b][s][h*128+o] bf16; l lives in col-0 lanes (l16==0)
    for (int mb = 0; mb < 2; ++mb) {
        for (int r = 0; r < 4; ++r) {
            float ls = __shfl(lacc[mb][r], lane & 48);  // broadcast from l16==0 of quad
            float inv = 1.f / ls;
            int s = q0 + wave * 32 + mb * 16 + quad * 4 + r;
            size_t base = ((size_t)b * S + s) * 1024 + h * 128;
            for (int oi = 0; oi < 8; ++oi)
                ctx[base + oi * 16 + l16] = f2bf(oacc[mb][oi][r] * inv);
        }
    }
}

// ---------------- launch ----------------

extern "C" void kernel_launch(void* const* d_in, const int* in_sizes, int n_in,
                              void* d_out, int out_size, void* d_ws, size_t ws_size,
                              hipStream_t stream) {
    const float* x  = (const float*)d_in[0];
    const float* Wq = (const float*)d_in[1];
    const float* Wk = (const float*)d_in[2];
    const float* Wv = (const float*)d_in[3];
    const float* Wo = (const float*)d_in[4];
    float* out = (float*)d_out;

    char* p = (char*)d_ws;
    auto alloc = [&](size_t bytes) { char* r = p; p += bytes; return r; };
    short* xh  = (short*)alloc(16777216);  // x hi    (8192 x 1024)
    short* xl  = (short*)alloc(16777216);  // x lo
    short* wth = (short*)alloc(2621440);   // Wt hi   (1280 x 1024)
    short* wtl = (short*)alloc(2621440);   // Wt lo
    short* wot = (short*)alloc(2097152);   // Wo^T    (1024 x 1024)
    short* qh  = (short*)alloc(16777216);  // Q hi    (B,H,S,D), pre-scaled
    short* ql  = (short*)alloc(16777216);  // Q lo
    short* kh  = (short*)alloc(2097152);   // K hi    (B,S,D)
    short* kl  = (short*)alloc(2097152);   // K lo
    short* vt  = (short*)alloc(2097152);   // V^T     (B,D,S)
    short* ctx = (short*)alloc(16777216);  // ctx     (B,S,H*D)

    prep_all<<<dim3(4352), dim3(256), 0, stream>>>(x, xh, xl, Wq, Wk, Wv,
                                                   wth, wtl, Wo, wot);
    gemm_k<0><<<dim3(64, 10), dim3(256), 0, stream>>>(xh, xl, wth, wtl,
                                                      qh, ql, kh, kl, vt, nullptr);
    attn_k<<<dim3(16, 32), dim3(256), 0, stream>>>(qh, ql, kh, kl, vt, ctx);
    gemm_k<1><<<dim3(64, 8), dim3(256), 0, stream>>>(ctx, nullptr, wot, nullptr,
                                                     nullptr, nullptr, nullptr, nullptr,
                                                     nullptr, out);
}

// Round 21
// 338.367 us; speedup vs baseline: 1.0725x; 1.0725x over previous
//
#include <hip/hip_runtime.h>
#include <math.h>

// ---------------------------------------------------------------------------
// Attention: B=4, S=2048, E=1024, H=8, O=128 (fp32 in/out)
// Split-bf16 (hi+lo) MFMA for x->QK and QK^T (precision-critical: score sd
// ~1500 exp2-domain log-units -> split terms are load-bearing; do NOT cut),
// plain bf16 for V / PV / ctx@Wo. Flash-attention (no S x S materialize).
// VERIFIED BEST: 336.1us (R18 cfg) / 338.9us (R24 cfg, noise-equiv).
// Attn facet ledger (all measured): staging latency (R10) neutral;
// occupancy (R11) regressed; softmax VALU (R12) neutral; phase-lockstep
// (R13/14) neutral; bank conflicts (R24) off critical path; drain volume
// via Kl-direct (R26) REGRESSED 167->190us (exposed L2 latency > drain
// savings; conflicts 8.4M->4.2M confirmed Kl_s as conflict source but
// MfmaUtil 36.5->31.2). R9 2-barrier attn structure at ~167us = robust
// local floor (825 TF issued-MFMA ~ m214 plain-HIP ladder).
// R27 (this round): REVERT R26 -> exact R24/R25 state.
// Future-session levers (high-risk structural): gemm0 8-phase counted-
// vmcnt port (T3/T4, +28-41% in learn_hip at 256^2); attn swapped-QK
// in-register softmax (m214). Both are multi-round rewrites.
// ---------------------------------------------------------------------------

typedef __attribute__((ext_vector_type(8))) short bf16x8;   // 8 bf16 (4 VGPRs)
typedef __attribute__((ext_vector_type(4))) float f32x4;
typedef __attribute__((ext_vector_type(4))) short s16x4;

#define MFMA(a, b, c) __builtin_amdgcn_mfma_f32_16x16x32_bf16((a), (b), (c), 0, 0, 0)
#define GLB(p) ((const __attribute__((address_space(1))) void*)(p))
#define LDS(p) ((__attribute__((address_space(3))) void*)(p))

#if __has_builtin(__builtin_amdgcn_exp2f)
#define EXP2F(x) __builtin_amdgcn_exp2f(x)
#else
#define EXP2F(x) exp2f(x)
#endif

__device__ __forceinline__ short f2bf(float f) {
    union { float f; unsigned u; } v; v.f = f;
    unsigned r = v.u + 0x7fffu + ((v.u >> 16) & 1u);   // RNE
    return (short)(r >> 16);
}
__device__ __forceinline__ float bf2f(short s) {
    union { unsigned u; float f; } v; v.u = ((unsigned)(unsigned short)s) << 16;
    return v.f;
}

// ---------------- fused prep kernel ----------------
// blocks [0,2048): x -> xh/xl split (float4/short4 vectorized)
// blocks [2048,3328): Wq/Wk/Wv -> Wt transpose (LDS tile, coalesced)
// blocks [3328,4352): Wo -> Wo^T bf16 transpose (LDS tile, coalesced)
__global__ __launch_bounds__(256) void prep_all(
    const float* __restrict__ x, short* __restrict__ xh, short* __restrict__ xl,
    const float* __restrict__ Wq, const float* __restrict__ Wk,
    const float* __restrict__ Wv, short* __restrict__ wth, short* __restrict__ wtl,
    const float* __restrict__ Wo, short* __restrict__ wot) {
    __shared__ float tile[32][33];
    const int bid = blockIdx.x, t = threadIdx.x;

    if (bid < 2048) {
        for (int i = bid * 256 + t; i < 2097152; i += 2048 * 256) {
            f32x4 v = *(const f32x4*)&x[(size_t)i * 4];
            s16x4 h, l;
            for (int j = 0; j < 4; ++j) {
                float f = v[j];
                short hh = f2bf(f);
                h[j] = hh;
                l[j] = f2bf(f - bf2f(hh));
            }
            *(s16x4*)&xh[(size_t)i * 4] = h;
            *(s16x4*)&xl[(size_t)i * 4] = l;
        }
        return;
    }

    if (bid < 3328) {
        const int l = bid - 2048;                   // old grid (32,4,10)
        const int m = l / 128, rem = l % 128;
        const int o0 = (rem / 32) * 32, k0 = (rem % 32) * 32;
        const float* src = (m < 8) ? (Wq + (size_t)m * 1024 * 128) : (m == 8 ? Wk : Wv);
        const int base_n = (m < 8) ? m * 128 : (m == 8 ? 1024 : 1152);
        {
            int tx = t & 31, ty = t >> 5;           // coalesced [k][o] loads
            for (int p = 0; p < 4; ++p)
                tile[ty + p * 8][tx] = src[(size_t)(k0 + ty + p * 8) * 128 + o0 + tx];
        }
        __syncthreads();
        {
            int kx = (t & 15) * 2, oy = t >> 4;     // coalesced [n][k] stores
            for (int p = 0; p < 2; ++p) {
                int o = oy + p * 16;
                float f0 = tile[kx][o], f1 = tile[kx + 1][o];
                short h0 = f2bf(f0), h1 = f2bf(f1);
                short l0 = f2bf(f0 - bf2f(h0)), l1 = f2bf(f1 - bf2f(h1));
                size_t oidx = (size_t)(base_n + o0 + o) * 1024 + k0 + kx;
                *(unsigned*)&wth[oidx] = (unsigned)(unsigned short)h0 |
                                         ((unsigned)(unsigned short)h1 << 16);
                *(unsigned*)&wtl[oidx] = (unsigned)(unsigned short)l0 |
                                         ((unsigned)(unsigned short)l1 << 16);
            }
        }
        return;
    }

    {
        const int l = bid - 3328;                   // old grid (32,32)
        const int k0 = (l & 31) * 32, e0 = (l >> 5) * 32;
        {
            int tx = t & 31, ty = t >> 5;
            for (int p = 0; p < 4; ++p)
                tile[ty + p * 8][tx] = Wo[(size_t)(k0 + ty + p * 8) * 1024 + e0 + tx];
        }
        __syncthreads();
        {
            int kx = (t & 15) * 2, ey = t >> 4;
            for (int p = 0; p < 2; ++p) {
                int e = ey + p * 16;
                float f0 = tile[kx][e], f1 = tile[kx + 1][e];
                short h0 = f2bf(f0), h1 = f2bf(f1);
                size_t oidx = (size_t)(e0 + e) * 1024 + k0 + kx;
                *(unsigned*)&wot[oidx] = (unsigned)(unsigned short)h0 |
                                         ((unsigned)(unsigned short)h1 << 16);
            }
        }
    }
}

// ---------------- GEMM: C(M x N) = A(M x 1024) @ Bt(N x 1024)^T ----------------
// K-tiles and epilogue staging share one LDS allocation (disjoint lifetimes,
// barrier-separated): 33.8 KB -> 4 blocks/CU.
// y==9 (V block) only consumes the hi result -> skip lo staging + lo MFMAs.
// XCD-clustered remap (verified -10us w/ prep fusion): XCD c owns
// bx===c(mod 8) x all by -> per-XCD set ~13 MB, A-reuse L2-resident.
template <int MODE>
__global__ __launch_bounds__(256, 4) void gemm_k(
    const short* __restrict__ Ah, const short* __restrict__ Al,
    const short* __restrict__ Bth, const short* __restrict__ Btl,
    short* __restrict__ qh, short* __restrict__ ql,
    short* __restrict__ kh, short* __restrict__ kl,
    short* __restrict__ vt, float* __restrict__ outf) {
    constexpr int K = 1024;
    constexpr int NY = (MODE == 0) ? 10 : 8;
    __shared__ __align__(16) char smem[33792];
    short* As_h = (short*)smem;                 // 128x32 = 8192 B
    short* Bs_h = (short*)(smem + 8192);
    short* As_l = (short*)(smem + 16384);       // MODE 0 only
    short* Bs_l = (short*)(smem + 24576);
    unsigned* Ep = (unsigned*)smem;             // 64x132 u32 = 33792 B (epilogue)

    const int t = threadIdx.x;
    const int L = blockIdx.y * gridDim.x + blockIdx.x;
    const int rg = L / (8 * NY), rr = L % (8 * NY);
    const int bx = rg * 8 + (rr & 7), by = rr >> 3;
    const int m0 = bx * 128, n0 = by * 128;
    const int wave = t >> 6, lane = t & 63;
    const int wr = wave >> 1, wc = wave & 1;
    const int quad = lane >> 4, l16 = lane & 15;
    const bool needLo = (MODE == 0) && (by < 9);   // V block skips lo

    f32x4 acc[4][4];
    for (int i = 0; i < 4; ++i)
        for (int j = 0; j < 4; ++j) acc[i][j] = (f32x4){0.f, 0.f, 0.f, 0.f};

    for (int kb = 0; kb < K / 32; ++kb) {
        __syncthreads();
        // DMA staging: each matrix = 512 slots of 16 B; 2 wave-insts per wave.
        for (int i = 0; i < 2; ++i) {
            int slot = (wave * 2 + i) * 64 + lane;
            int row = slot >> 2, ch = slot & 3;
            int ldsoff = (wave * 2 + i) * 512;  // shorts; +lane*16B by HW
            size_t ga = (size_t)(m0 + row) * K + kb * 32 + ch * 8;
            size_t gb = (size_t)(n0 + row) * K + kb * 32 + ch * 8;
            __builtin_amdgcn_global_load_lds(GLB(Ah + ga), LDS(&As_h[ldsoff]), 16, 0, 0);
            __builtin_amdgcn_global_load_lds(GLB(Bth + gb), LDS(&Bs_h[ldsoff]), 16, 0, 0);
            if constexpr (MODE == 0) {
                if (needLo) {
                    __builtin_amdgcn_global_load_lds(GLB(Al + ga), LDS(&As_l[ldsoff]), 16, 0, 0);
                    __builtin_amdgcn_global_load_lds(GLB(Btl + gb), LDS(&Bs_l[ldsoff]), 16, 0, 0);
                }
            }
        }
        __syncthreads();

        bf16x8 a[4], b[4];
        for (int mi = 0; mi < 4; ++mi)
            a[mi] = *(const bf16x8*)&As_h[(wr * 64 + mi * 16 + l16) * 32 + quad * 8];
        for (int ni = 0; ni < 4; ++ni)
            b[ni] = *(const bf16x8*)&Bs_h[(wc * 64 + ni * 16 + l16) * 32 + quad * 8];
        for (int mi = 0; mi < 4; ++mi)
            for (int ni = 0; ni < 4; ++ni)
                acc[mi][ni] = MFMA(a[mi], b[ni], acc[mi][ni]);
        if constexpr (MODE == 0) {
            if (needLo) {
                bf16x8 al[4], bl[4];
                for (int mi = 0; mi < 4; ++mi)
                    al[mi] = *(const bf16x8*)&As_l[(wr * 64 + mi * 16 + l16) * 32 + quad * 8];
                for (int ni = 0; ni < 4; ++ni)
                    bl[ni] = *(const bf16x8*)&Bs_l[(wc * 64 + ni * 16 + l16) * 32 + quad * 8];
                for (int mi = 0; mi < 4; ++mi)
                    for (int ni = 0; ni < 4; ++ni) {
                        acc[mi][ni] = MFMA(a[mi], bl[ni], acc[mi][ni]);
                        acc[mi][ni] = MFMA(al[mi], b[ni], acc[mi][ni]);
                    }
            }
        }
    }

    // LDS-staged epilogue (C/D layout: col=l16, row=quad*4+r).
    // Q columns pre-scaled by (1/sqrt(128))*log2(e) for exp2-domain softmax.
    const float qscale = 0.12753102455195157f;
    for (int p = 0; p < 2; ++p) {
        __syncthreads();   // also separates K-loop tile reads from Ep writes
        if (wr == p) {
            for (int mi = 0; mi < 4; ++mi) {
                int rl = mi * 16 + quad * 4;
                for (int ni = 0; ni < 4; ++ni) {
                    int cl = wc * 64 + ni * 16 + l16;
                    for (int r = 0; r < 4; ++r) {
                        float v = acc[mi][ni][r];
                        unsigned pk;
                        if constexpr (MODE == 0) {
                            if (by < 8) v *= qscale;
                            short hv = f2bf(v);
                            short lv = f2bf(v - bf2f(hv));
                            pk = (unsigned)(unsigned short)hv |
                                 ((unsigned)(unsigned short)lv << 16);
                        } else {
                            union { float f; unsigned u; } cv; cv.f = v; pk = cv.u;
                        }
                        Ep[(rl + r) * 132 + cl] = pk;
                    }
                }
            }
        }
        __syncthreads();

        if constexpr (MODE == 1) {
            for (int j = 0; j < 8; ++j) {
                int cid = t + j * 256;
                int row = cid >> 5, c = cid & 31;
                f32x4 val;
                for (int q = 0; q < 4; ++q) {
                    union { unsigned u; float f; } cv;
                    cv.u = Ep[row * 132 + c * 4 + q];
                    val[q] = cv.f;
                }
                int gr = m0 + p * 64 + row;
                *(f32x4*)&outf[(size_t)gr * 1024 + n0 + c * 4] = val;
            }
        } else if (by < 9) {
            for (int j = 0; j < 4; ++j) {
                int cid = t + j * 256;
                int row = cid >> 4, c = cid & 15;
                bf16x8 hv, lv;
                for (int q = 0; q < 8; ++q) {
                    unsigned w = Ep[row * 132 + c * 8 + q];
                    hv[q] = (short)(w & 0xffffu);
                    lv[q] = (short)(w >> 16);
                }
                int gr = m0 + p * 64 + row;
                int bb = gr >> 11, s = gr & 2047;
                if (by < 8) {
                    size_t base = (((size_t)(bb * 8 + (n0 >> 7))) * 2048 + s) * 128 + c * 8;
                    *(bf16x8*)&qh[base] = hv;
                    *(bf16x8*)&ql[base] = lv;
                } else {
                    size_t base = ((size_t)bb * 2048 + s) * 128 + c * 8;
                    *(bf16x8*)&kh[base] = hv;
                    *(bf16x8*)&kl[base] = lv;
                }
            }
        } else {
            for (int j = 0; j < 4; ++j) {
                int cid = t + j * 256;
                int d = cid >> 3, sc = cid & 7;
                bf16x8 hv;
                for (int q = 0; q < 8; ++q) {
                    unsigned w = Ep[(sc * 8 + q) * 132 + d];
                    hv[q] = (short)(w & 0xffffu);
                }
                int gr0 = m0 + p * 64 + sc * 8;
                int bb = gr0 >> 11, s0 = gr0 & 2047;
                *(bf16x8*)&vt[((size_t)bb * 128 + d) * 2048 + s0] = hv;
            }
        }
    }
}

// ---------------- flash attention (R9 structure + P_s stride 68) ----------------
// grid (S/128, B*H); 4 waves x 32 query rows (2 m-blocks); BN=64 keys/iter.
// K/V staged via global_load_lds with XOR-swizzled chunks between the two
// barriers. setprio(1) around MFMA clusters. P_s stride 68 (R24).
__global__ __launch_bounds__(256, 2) void attn_k(
    const short* __restrict__ qh, const short* __restrict__ ql,
    const short* __restrict__ kh, const short* __restrict__ kl,
    const short* __restrict__ vt, short* __restrict__ ctx) {
    constexpr int S = 2048, D = 128;
    constexpr int PS = 68;              // P_s row stride (shorts)
    __shared__ short Kh_s[64 * 128];    // swizzled, no pad
    __shared__ short Kl_s[64 * 128];
    __shared__ short Vt_s[128 * 64];    // swizzled, no pad
    __shared__ short P_s[128 * PS];     // per-wave 32-row slices

    const int bh = blockIdx.y, b = bh >> 3, h = bh & 7;
    const int q0 = blockIdx.x * 128;
    const int t = threadIdx.x, wave = t >> 6, lane = t & 63;
    const int quad = lane >> 4, l16 = lane & 15;
    const int e8 = l16 & 7;             // xor-swizzle key

    // ones B-fragment: B[n=l16][k] = (n==0) ? 1.0bf16 : 0  -> C[., col0] = rowsum
    bf16x8 bones;
    {
        short o = (l16 == 0) ? (short)0x3F80 : (short)0;
        for (int j = 0; j < 8; ++j) bones[j] = o;
    }

    // Q fragments (A-layout A[m=l16][k=quad*8+j]), 2 m-blocks x 4 k-chunks
    bf16x8 qfh[2][4], qfl[2][4];
    for (int mb = 0; mb < 2; ++mb) {
        size_t qbase = ((size_t)(b * 8 + h) * S + q0 + wave * 32 + mb * 16 + l16) * D + quad * 8;
        for (int c = 0; c < 4; ++c) {
            qfh[mb][c] = *(const bf16x8*)(qh + qbase + c * 32);
            qfl[mb][c] = *(const bf16x8*)(ql + qbase + c * 32);
        }
    }

    float mrow[2][4];
    f32x4 oacc[2][8], lacc[2];
    for (int mb = 0; mb < 2; ++mb) {
        for (int r = 0; r < 4; ++r) mrow[mb][r] = -INFINITY;
        for (int oi = 0; oi < 8; ++oi) oacc[mb][oi] = (f32x4){0.f, 0.f, 0.f, 0.f};
        lacc[mb] = (f32x4){0.f, 0.f, 0.f, 0.f};
    }

    for (int kt = 0; kt < S / 64; ++kt) {
        __syncthreads();  // protect LDS reuse
        // --- stage K hi/lo: 64 rows x 128 ---
        {
            int pch = lane & 15;
            for (int i = 0; i < 4; ++i) {
                int rk = wave * 16 + i * 4 + (lane >> 4);
                int j = pch ^ (rk & 7);
                size_t g = ((size_t)b * S + kt * 64 + rk) * D + j * 8;
                int ldsoff = (wave * 16 + i * 4) * 128;
                __builtin_amdgcn_global_load_lds(GLB(kh + g), LDS(&Kh_s[ldsoff]), 16, 0, 0);
                __builtin_amdgcn_global_load_lds(GLB(kl + g), LDS(&Kl_s[ldsoff]), 16, 0, 0);
            }
        }
        // --- stage V^T: 128 rows(o) x 64(s) ---
        {
            int pch = lane & 7;
            for (int i = 0; i < 4; ++i) {
                int rv = wave * 32 + i * 8 + (lane >> 3);
                int j = pch ^ (rv & 7);
                size_t g = ((size_t)b * D + rv) * S + kt * 64 + j * 8;
                int ldsoff = (wave * 32 + i * 8) * 64;
                __builtin_amdgcn_global_load_lds(GLB(vt + g), LDS(&Vt_s[ldsoff]), 16, 0, 0);
            }
        }
        __syncthreads();

        // --- S' = Q' K^T (split: hh + lh + hl); scores already * scale*log2e ---
        f32x4 sacc[2][4];
        for (int mb = 0; mb < 2; ++mb)
            for (int ni = 0; ni < 4; ++ni) sacc[mb][ni] = (f32x4){0.f, 0.f, 0.f, 0.f};
        for (int ni = 0; ni < 4; ++ni) {
            for (int c = 0; c < 4; ++c) {
                int off = (ni * 16 + l16) * 128 + ((c * 4 + quad) ^ e8) * 8;
                bf16x8 kbh = *(const bf16x8*)&Kh_s[off];
                bf16x8 kbl = *(const bf16x8*)&Kl_s[off];
                __builtin_amdgcn_s_setprio(1);
                for (int mb = 0; mb < 2; ++mb) {
                    sacc[mb][ni] = MFMA(qfh[mb][c], kbh, sacc[mb][ni]);
                    sacc[mb][ni] = MFMA(qfl[mb][c], kbh, sacc[mb][ni]);
                    sacc[mb][ni] = MFMA(qfh[mb][c], kbl, sacc[mb][ni]);
                }
                __builtin_amdgcn_s_setprio(0);
            }
        }

        // --- online softmax (exp2 domain); rows quad*4+r per m-block ---
        for (int mb = 0; mb < 2; ++mb) {
            for (int r = 0; r < 4; ++r) {
                float mx = fmaxf(fmaxf(sacc[mb][0][r], sacc[mb][1][r]),
                                 fmaxf(sacc[mb][2][r], sacc[mb][3][r]));
                for (int off = 8; off; off >>= 1) mx = fmaxf(mx, __shfl_xor(mx, off));
                float mnew = fmaxf(mrow[mb][r], mx);
                float alpha = EXP2F(mrow[mb][r] - mnew);
                mrow[mb][r] = mnew;
                for (int ni = 0; ni < 4; ++ni)
                    sacc[mb][ni][r] = EXP2F(sacc[mb][ni][r] - mnew);
                lacc[mb][r] *= alpha;
                for (int oi = 0; oi < 8; ++oi) oacc[mb][oi][r] *= alpha;
            }
            // P -> LDS (C-layout -> A-layout); round-half-up bf16 (2 ops)
            for (int ni = 0; ni < 4; ++ni)
                for (int r = 0; r < 4; ++r) {
                    union { float f; unsigned u; } cv; cv.f = sacc[mb][ni][r];
                    P_s[(wave * 32 + mb * 16 + quad * 4 + r) * PS + ni * 16 + l16] =
                        (short)((cv.u + 0x8000u) >> 16);
                }
        }

        // --- O += P @ V ; l += P @ ones (MFMA) ---
        for (int c2 = 0; c2 < 2; ++c2) {
            bf16x8 pa[2];
            for (int mb = 0; mb < 2; ++mb) {
                pa[mb] = *(const bf16x8*)&P_s[(wave * 32 + mb * 16 + l16) * PS + c2 * 32 + quad * 8];
                lacc[mb] = MFMA(pa[mb], bones, lacc[mb]);
            }
            for (int oi = 0; oi < 8; ++oi) {
                int off = (oi * 16 + l16) * 64 + ((c2 * 4 + quad) ^ e8) * 8;
                bf16x8 vb = *(const bf16x8*)&Vt_s[off];
                __builtin_amdgcn_s_setprio(1);
                for (int mb = 0; mb < 2; ++mb)
                    oacc[mb][oi] = MFMA(pa[mb], vb, oacc[mb][oi]);
                __builtin_amdgcn_s_setprio(0);
            }
        }
    }

    // epilogue: ctx[b][s][h*128+o] bf16; l lives in col-0 lanes (l16==0)
    for (int mb = 0; mb < 2; ++mb) {
        for (int r = 0; r < 4; ++r) {
            float ls = __shfl(lacc[mb][r], lane & 48);  // broadcast from l16==0 of quad
            float inv = 1.f / ls;
            int s = q0 + wave * 32 + mb * 16 + quad * 4 + r;
            size_t base = ((size_t)b * S + s) * 1024 + h * 128;
            for (int oi = 0; oi < 8; ++oi)
                ctx[base + oi * 16 + l16] = f2bf(oacc[mb][oi][r] * inv);
        }
    }
}

// ---------------- launch ----------------

extern "C" void kernel_launch(void* const* d_in, const int* in_sizes, int n_in,
                              void* d_out, int out_size, void* d_ws, size_t ws_size,
                              hipStream_t stream) {
    const float* x  = (const float*)d_in[0];
    const float* Wq = (const float*)d_in[1];
    const float* Wk = (const float*)d_in[2];
    const float* Wv = (const float*)d_in[3];
    const float* Wo = (const float*)d_in[4];
    float* out = (float*)d_out;

    char* p = (char*)d_ws;
    auto alloc = [&](size_t bytes) { char* r = p; p += bytes; return r; };
    short* xh  = (short*)alloc(16777216);  // x hi    (8192 x 1024)
    short* xl  = (short*)alloc(16777216);  // x lo
    short* wth = (short*)alloc(2621440);   // Wt hi   (1280 x 1024)
    short* wtl = (short*)alloc(2621440);   // Wt lo
    short* wot = (short*)alloc(2097152);   // Wo^T    (1024 x 1024)
    short* qh  = (short*)alloc(16777216);  // Q hi    (B,H,S,D), pre-scaled
    short* ql  = (short*)alloc(16777216);  // Q lo
    short* kh  = (short*)alloc(2097152);   // K hi    (B,S,D)
    short* kl  = (short*)alloc(2097152);   // K lo
    short* vt  = (short*)alloc(2097152);   // V^T     (B,D,S)
    short* ctx = (short*)alloc(16777216);  // ctx     (B,S,H*D)

    prep_all<<<dim3(4352), dim3(256), 0, stream>>>(x, xh, xl, Wq, Wk, Wv,
                                                   wth, wtl, Wo, wot);
    gemm_k<0><<<dim3(64, 10), dim3(256), 0, stream>>>(xh, xl, wth, wtl,
                                                      qh, ql, kh, kl, vt, nullptr);
    attn_k<<<dim3(16, 32), dim3(256), 0, stream>>>(qh, ql, kh, kl, vt, ctx);
    gemm_k<1><<<dim3(64, 8), dim3(256), 0, stream>>>(ctx, nullptr, wot, nullptr,
                                                     nullptr, nullptr, nullptr, nullptr,
                                                     nullptr, out);
}